// Round 1
// baseline (1112.702 us; speedup 1.0000x reference)
//
#include <hip/hip_runtime.h>
#include <hip/hip_bf16.h>
#include <math.h>

typedef __attribute__((ext_vector_type(8))) short short8;
typedef __attribute__((ext_vector_type(4))) float f32x4;

#define MFMA16(a,b,c) __builtin_amdgcn_mfma_f32_16x16x32_bf16((a),(b),(c),0,0,0)

__device__ __forceinline__ unsigned short f2bf(float f){
  unsigned int u = __builtin_bit_cast(unsigned int, f);
  u += 0x7fffu + ((u >> 16) & 1u);
  return (unsigned short)(u >> 16);
}

__device__ __forceinline__ void gload16(const void* g, void* lds){
  __builtin_amdgcn_global_load_lds(
      (const __attribute__((address_space(1))) unsigned int*)g,
      (__attribute__((address_space(3))) unsigned int*)lds, 16, 0, 0);
}

// ---------------- weight transpose + cast: in [K][N] f32 -> out [N][K] bf16 ----------------
__global__ __launch_bounds__(256) void k_transpose_cast(const float* __restrict__ in,
    unsigned short* __restrict__ out, int K, int N)
{
  __shared__ unsigned short tile[32][33];
  const int tx = threadIdx.x, ty = threadIdx.y;
  const int n0 = blockIdx.x * 32, k0 = blockIdx.y * 32;
  #pragma unroll
  for (int i = 0; i < 4; i++) {
    int k = k0 + ty + i*8;
    tile[ty + i*8][tx] = f2bf(in[(size_t)k * N + n0 + tx]);
  }
  __syncthreads();
  #pragma unroll
  for (int i = 0; i < 4; i++) {
    int n = n0 + ty + i*8;
    out[(size_t)n * K + k0 + tx] = tile[tx][ty + i*8];
  }
}

// ---------------- layernorm: x [rows][1024] f32 -> out bf16 ----------------
__global__ __launch_bounds__(256) void k_layernorm(const float* __restrict__ x,
    const float* __restrict__ g, const float* __restrict__ b,
    unsigned short* __restrict__ out)
{
  const int row = blockIdx.x;
  const int t = threadIdx.x;
  const float4 v = ((const float4*)(x + (size_t)row * 1024))[t];
  float s  = v.x + v.y + v.z + v.w;
  float s2 = v.x*v.x + v.y*v.y + v.z*v.z + v.w*v.w;
  #pragma unroll
  for (int m = 1; m < 64; m <<= 1) {
    s  += __shfl_xor(s,  m);
    s2 += __shfl_xor(s2, m);
  }
  __shared__ float red[2][4];
  const int wid = t >> 6, lane = t & 63;
  if (lane == 0) { red[0][wid] = s; red[1][wid] = s2; }
  __syncthreads();
  s  = red[0][0] + red[0][1] + red[0][2] + red[0][3];
  s2 = red[1][0] + red[1][1] + red[1][2] + red[1][3];
  const float mu = s * (1.0f / 1024.0f);
  const float var = s2 * (1.0f / 1024.0f) - mu * mu;
  const float rstd = rsqrtf(var + 1e-6f);
  const float4 gv = ((const float4*)g)[t];
  const float4 bv = ((const float4*)b)[t];
  ushort4 o;
  o.x = f2bf((v.x - mu) * rstd * gv.x + bv.x);
  o.y = f2bf((v.y - mu) * rstd * gv.y + bv.y);
  o.z = f2bf((v.z - mu) * rstd * gv.z + bv.z);
  o.w = f2bf((v.w - mu) * rstd * gv.w + bv.w);
  ((ushort4*)(out + (size_t)row * 1024))[t] = o;
}

// ---------------- MFMA GEMM: C[M][N] = A[M][K](bf16) * Bt[N][K]^T(bf16) + epilogue ----------------
// EPI 0: out bf16 = acc + bias
// EPI 1: out bf16 = gelu_exact(acc + bias)
// EPI 2: out f32  = resid + (acc + bias) * lsg
template<int EPI>
__global__ __launch_bounds__(256) void k_gemm(
    const unsigned short* __restrict__ A,
    const unsigned short* __restrict__ Bt,
    const float* __restrict__ bias,
    const float* __restrict__ resid,
    const float* __restrict__ lsg,
    void* __restrict__ outp,
    int M, int N, int K)
{
  __shared__ __align__(16) unsigned short Asm[128 * 32];
  __shared__ __align__(16) unsigned short Bsm[128 * 32];
  const int bm = blockIdx.x, bn = blockIdx.y;
  const int t = threadIdx.x, lane = t & 63;
  const int wid = t >> 6, wm = wid >> 1, wn = wid & 1;
  f32x4 acc[4][4] = {};
  const int fr = lane & 15, kc = (lane >> 4) * 8;
  const size_t arow0 = (size_t)bm * 128;
  const size_t brow0 = (size_t)bn * 128;
  const int c0 = t, c1 = 256 + t;
  const int r0c = c0 >> 2, g0c = (c0 & 3) * 8;
  const int r1c = c1 >> 2, g1c = (c1 & 3) * 8;

  for (int kt = 0; kt < K; kt += 32) {
    __syncthreads();
    gload16(A  + (arow0 + r0c) * K + kt + g0c, (char*)Asm + (size_t)c0 * 16);
    gload16(Bt + (brow0 + r0c) * K + kt + g0c, (char*)Bsm + (size_t)c0 * 16);
    gload16(A  + (arow0 + r1c) * K + kt + g1c, (char*)Asm + (size_t)c1 * 16);
    gload16(Bt + (brow0 + r1c) * K + kt + g1c, (char*)Bsm + (size_t)c1 * 16);
    __syncthreads();
    short8 af[4], bfr[4];
    #pragma unroll
    for (int m = 0; m < 4; m++)
      af[m] = *(const short8*)&Asm[(wm*64 + m*16 + fr) * 32 + kc];
    #pragma unroll
    for (int n = 0; n < 4; n++)
      bfr[n] = *(const short8*)&Bsm[(wn*64 + n*16 + fr) * 32 + kc];
    #pragma unroll
    for (int m = 0; m < 4; m++)
      #pragma unroll
      for (int n = 0; n < 4; n++)
        acc[m][n] = MFMA16(af[m], bfr[n], acc[m][n]);
  }

  const int row0 = bm*128 + wm*64 + (lane >> 4) * 4;
  const int col0 = bn*128 + wn*64 + fr;
  #pragma unroll
  for (int n = 0; n < 4; n++) {
    const int col = col0 + n*16;
    const float bcol = bias[col];
    float lscale = 0.f;
    if (EPI == 2) lscale = lsg[col];
    #pragma unroll
    for (int m = 0; m < 4; m++) {
      #pragma unroll
      for (int r = 0; r < 4; r++) {
        const int row = row0 + m*16 + r;
        float v = acc[m][n][r] + bcol;
        if (EPI == 0) {
          ((unsigned short*)outp)[(size_t)row * N + col] = f2bf(v);
        } else if (EPI == 1) {
          v = 0.5f * v * (1.0f + erff(v * 0.70710678118654752f));
          ((unsigned short*)outp)[(size_t)row * N + col] = f2bf(v);
        } else {
          ((float*)outp)[(size_t)row * N + col] =
              resid[(size_t)row * N + col] + v * lscale;
        }
      }
    }
  }
}

// ---------------- flash attention (no 1/sqrt(d) scale, faithful to ref) ----------------
// qkv: [16384][3072] bf16, row = b*1024+n, col = which*1024 + h*64 + d
// out: [16384][1024] bf16 (col = h*64 + d)
__global__ __launch_bounds__(256) void k_attn(const unsigned short* __restrict__ qkv,
                                              unsigned short* __restrict__ out)
{
  const int qt = blockIdx.x;       // 0..15  (q tile of 64 rows)
  const int bh = blockIdx.y;       // 0..255
  const int b = bh >> 4, h = bh & 15;
  const int t = threadIdx.x, lane = t & 63, wid = t >> 6;
  const int q0 = qt * 64 + wid * 16;
  const size_t RS = 3072;
  const size_t base = (size_t)b * 1024 * RS;

  // Q fragments (each wave owns 16 q rows)
  short8 qf0, qf1;
  {
    const unsigned short* qp = qkv + base + (size_t)(q0 + (lane & 15)) * RS
                               + h * 64 + ((lane >> 4) * 8);
    qf0 = *(const short8*)qp;
    qf1 = *(const short8*)(qp + 32);
  }

  f32x4 oacc[4] = {};
  float mrow[4], lrow[4];
  #pragma unroll
  for (int r = 0; r < 4; r++) { mrow[r] = -1e30f; lrow[r] = 0.f; }

  __shared__ __align__(16) unsigned short vt[64][72];        // V^T [d][kv], padded
  __shared__ __align__(16) unsigned short plds[4][16][72];   // per-wave P [qrow][kv], padded

  const int vkv = t >> 2;            // kv row staged by this thread
  const int vd0 = (t & 3) * 16;      // d group

  for (int kv0 = 0; kv0 < 1024; kv0 += 64) {
    __syncthreads();
    // stage V^T tile
    {
      const unsigned short* vp = qkv + base + (size_t)(kv0 + vkv) * RS
                                 + 2048 + h * 64 + vd0;
      short8 v0 = *(const short8*)vp;
      short8 v1 = *(const short8*)(vp + 8);
      #pragma unroll
      for (int j = 0; j < 8; j++) vt[vd0 + j][vkv]     = (unsigned short)v0[j];
      #pragma unroll
      for (int j = 0; j < 8; j++) vt[vd0 + 8 + j][vkv] = (unsigned short)v1[j];
    }
    __syncthreads();

    // S = Q K^T  (16 x 64 per wave)
    f32x4 sacc[4] = {};
    #pragma unroll
    for (int n16 = 0; n16 < 4; n16++) {
      const unsigned short* kp = qkv + base + (size_t)(kv0 + n16*16 + (lane & 15)) * RS
                                 + 1024 + h * 64 + ((lane >> 4) * 8);
      short8 kf0 = *(const short8*)kp;
      short8 kf1 = *(const short8*)(kp + 32);
      sacc[n16] = MFMA16(qf0, kf0, sacc[n16]);
      sacc[n16] = MFMA16(qf1, kf1, sacc[n16]);
    }

    // online softmax (row r of this lane = q0 + (lane>>4)*4 + r)
    float pm[4];
    #pragma unroll
    for (int r = 0; r < 4; r++) {
      pm[r] = fmaxf(fmaxf(sacc[0][r], sacc[1][r]), fmaxf(sacc[2][r], sacc[3][r]));
    }
    #pragma unroll
    for (int msk = 1; msk < 16; msk <<= 1) {
      #pragma unroll
      for (int r = 0; r < 4; r++) pm[r] = fmaxf(pm[r], __shfl_xor(pm[r], msk));
    }
    float corr[4];
    #pragma unroll
    for (int r = 0; r < 4; r++) {
      float mn = fmaxf(mrow[r], pm[r]);
      corr[r] = __expf(mrow[r] - mn);
      mrow[r] = mn;
    }
    float psum[4] = {0.f, 0.f, 0.f, 0.f};
    #pragma unroll
    for (int n16 = 0; n16 < 4; n16++) {
      #pragma unroll
      for (int r = 0; r < 4; r++) {
        float p = __expf(sacc[n16][r] - mrow[r]);
        sacc[n16][r] = p;
        psum[r] += p;
      }
    }
    #pragma unroll
    for (int msk = 1; msk < 16; msk <<= 1) {
      #pragma unroll
      for (int r = 0; r < 4; r++) psum[r] += __shfl_xor(psum[r], msk);
    }
    #pragma unroll
    for (int r = 0; r < 4; r++) lrow[r] = lrow[r] * corr[r] + psum[r];
    #pragma unroll
    for (int d16 = 0; d16 < 4; d16++)
      #pragma unroll
      for (int r = 0; r < 4; r++) oacc[d16][r] *= corr[r];

    // P -> LDS (per-wave region), then read as A-fragments
    #pragma unroll
    for (int n16 = 0; n16 < 4; n16++)
      #pragma unroll
      for (int r = 0; r < 4; r++)
        plds[wid][(lane >> 4) * 4 + r][n16 * 16 + (lane & 15)] = f2bf(sacc[n16][r]);

    short8 pf0 = *(const short8*)&plds[wid][lane & 15][(lane >> 4) * 8];
    short8 pf1 = *(const short8*)&plds[wid][lane & 15][32 + (lane >> 4) * 8];

    // O += P V
    #pragma unroll
    for (int d16 = 0; d16 < 4; d16++) {
      short8 vf0 = *(const short8*)&vt[d16 * 16 + (lane & 15)][(lane >> 4) * 8];
      short8 vf1 = *(const short8*)&vt[d16 * 16 + (lane & 15)][32 + (lane >> 4) * 8];
      oacc[d16] = MFMA16(pf0, vf0, oacc[d16]);
      oacc[d16] = MFMA16(pf1, vf1, oacc[d16]);
    }
  }

  float inv[4];
  #pragma unroll
  for (int r = 0; r < 4; r++) inv[r] = 1.0f / lrow[r];
  #pragma unroll
  for (int d16 = 0; d16 < 4; d16++) {
    #pragma unroll
    for (int r = 0; r < 4; r++) {
      const int row = q0 + (lane >> 4) * 4 + r;
      const int col = h * 64 + d16 * 16 + (lane & 15);
      out[(size_t)(b * 1024 + row) * 1024 + col] = f2bf(oacc[d16][r] * inv[r]);
    }
  }
}

// ---------------- host launch ----------------
extern "C" void kernel_launch(void* const* d_in, const int* in_sizes, int n_in,
                              void* d_out, int out_size, void* d_ws, size_t ws_size,
                              hipStream_t stream) {
  const float* x      = (const float*)d_in[0];
  const float* ln1_g  = (const float*)d_in[1];
  const float* ln1_b  = (const float*)d_in[2];
  const float* qkv_w  = (const float*)d_in[3];
  const float* qkv_b  = (const float*)d_in[4];
  const float* proj_w = (const float*)d_in[5];
  const float* proj_b = (const float*)d_in[6];
  const float* ls1_g  = (const float*)d_in[7];
  const float* ln2_g  = (const float*)d_in[8];
  const float* ln2_b  = (const float*)d_in[9];
  const float* fc1_w  = (const float*)d_in[10];
  const float* fc1_b  = (const float*)d_in[11];
  const float* fc2_w  = (const float*)d_in[12];
  const float* fc2_b  = (const float*)d_in[13];
  const float* ls2_g  = (const float*)d_in[14];

  char* w = (char*)d_ws;
  // workspace layout (bytes)
  unsigned short* wqkvT  = (unsigned short*)(w + 0);                    //  6,291,456
  unsigned short* wprojT = (unsigned short*)(w + 6291456);              //  2,097,152
  unsigned short* wfc1T  = (unsigned short*)(w + 8388608);              //  8,388,608
  unsigned short* wfc2T  = (unsigned short*)(w + 16777216);             //  8,388,608
  float*          x1     = (float*)(w + 25165824);                      // 67,108,864
  unsigned short* h1     = (unsigned short*)(w + 92274688);             // 33,554,432 (reused as h2)
  unsigned short* qkvbuf = (unsigned short*)(w + 125829120);            // 100,663,296
  unsigned short* attno  = (unsigned short*)(w + 226492416);            // 33,554,432
  unsigned short* h3     = (unsigned short*)(w + 125829120);            // 134,217,728 (overlays qkv+attno)

  dim3 tb32(32, 8);
  // weight prep: [K][N] f32 -> [N][K] bf16
  k_transpose_cast<<<dim3(3072/32, 1024/32), tb32, 0, stream>>>(qkv_w,  wqkvT, 1024, 3072);
  k_transpose_cast<<<dim3(1024/32, 1024/32), tb32, 0, stream>>>(proj_w, wprojT, 1024, 1024);
  k_transpose_cast<<<dim3(4096/32, 1024/32), tb32, 0, stream>>>(fc1_w,  wfc1T, 1024, 4096);
  k_transpose_cast<<<dim3(1024/32, 4096/32), tb32, 0, stream>>>(fc2_w,  wfc2T, 4096, 1024);

  // LN1
  k_layernorm<<<16384, 256, 0, stream>>>(x, ln1_g, ln1_b, h1);
  // QKV = h1 @ qkv_w + qkv_b   [16384 x 3072]
  k_gemm<0><<<dim3(128, 24), 256, 0, stream>>>(h1, wqkvT, qkv_b, nullptr, nullptr,
                                               qkvbuf, 16384, 3072, 1024);
  // attention
  k_attn<<<dim3(16, 256), 256, 0, stream>>>(qkvbuf, attno);
  // x1 = x + (attn @ proj_w + proj_b) * ls1_g
  k_gemm<2><<<dim3(128, 8), 256, 0, stream>>>(attno, wprojT, proj_b, x, ls1_g,
                                              x1, 16384, 1024, 1024);
  // LN2
  k_layernorm<<<16384, 256, 0, stream>>>(x1, ln2_g, ln2_b, h1);
  // h3 = gelu(h2 @ fc1_w + fc1_b)  [16384 x 4096]
  k_gemm<1><<<dim3(128, 32), 256, 0, stream>>>(h1, wfc1T, fc1_b, nullptr, nullptr,
                                               h3, 16384, 4096, 1024);
  // out = x1 + (h3 @ fc2_w + fc2_b) * ls2_g
  k_gemm<2><<<dim3(128, 8), 256, 0, stream>>>(h3, wfc2T, fc2_b, x1, ls2_g,
                                              (float*)d_out, 16384, 1024, 4096);
}

// Round 2
// 1023.330 us; speedup vs baseline: 1.0873x; 1.0873x over previous
//
#include <hip/hip_runtime.h>
#include <hip/hip_bf16.h>
#include <math.h>

typedef __attribute__((ext_vector_type(8))) short short8;
typedef __attribute__((ext_vector_type(4))) float f32x4;

#define MFMA16(a,b,c) __builtin_amdgcn_mfma_f32_16x16x32_bf16((a),(b),(c),0,0,0)

__device__ __forceinline__ unsigned short f2bf(float f){
  unsigned int u = __builtin_bit_cast(unsigned int, f);
  u += 0x7fffu + ((u >> 16) & 1u);
  return (unsigned short)(u >> 16);
}

__device__ __forceinline__ void gload16(const void* g, void* lds){
  __builtin_amdgcn_global_load_lds(
      (const __attribute__((address_space(1))) unsigned int*)g,
      (__attribute__((address_space(3))) unsigned int*)lds, 16, 0, 0);
}

// ---------------- weight transpose + cast: in [K][N] f32 -> out [N][K] bf16 ----------------
__global__ __launch_bounds__(256) void k_transpose_cast(const float* __restrict__ in,
    unsigned short* __restrict__ out, int K, int N)
{
  __shared__ unsigned short tile[32][33];
  const int tx = threadIdx.x, ty = threadIdx.y;
  const int n0 = blockIdx.x * 32, k0 = blockIdx.y * 32;
  #pragma unroll
  for (int i = 0; i < 4; i++) {
    int k = k0 + ty + i*8;
    tile[ty + i*8][tx] = f2bf(in[(size_t)k * N + n0 + tx]);
  }
  __syncthreads();
  #pragma unroll
  for (int i = 0; i < 4; i++) {
    int n = n0 + ty + i*8;
    out[(size_t)n * K + k0 + tx] = tile[tx][ty + i*8];
  }
}

// ---------------- layernorm: x [rows][1024] f32 -> out bf16 ----------------
__global__ __launch_bounds__(256) void k_layernorm(const float* __restrict__ x,
    const float* __restrict__ g, const float* __restrict__ b,
    unsigned short* __restrict__ out)
{
  const int row = blockIdx.x;
  const int t = threadIdx.x;
  const float4 v = ((const float4*)(x + (size_t)row * 1024))[t];
  float s  = v.x + v.y + v.z + v.w;
  float s2 = v.x*v.x + v.y*v.y + v.z*v.z + v.w*v.w;
  #pragma unroll
  for (int m = 1; m < 64; m <<= 1) {
    s  += __shfl_xor(s,  m);
    s2 += __shfl_xor(s2, m);
  }
  __shared__ float red[2][4];
  const int wid = t >> 6, lane = t & 63;
  if (lane == 0) { red[0][wid] = s; red[1][wid] = s2; }
  __syncthreads();
  s  = red[0][0] + red[0][1] + red[0][2] + red[0][3];
  s2 = red[1][0] + red[1][1] + red[1][2] + red[1][3];
  const float mu = s * (1.0f / 1024.0f);
  const float var = s2 * (1.0f / 1024.0f) - mu * mu;
  const float rstd = rsqrtf(var + 1e-6f);
  const float4 gv = ((const float4*)g)[t];
  const float4 bv = ((const float4*)b)[t];
  ushort4 o;
  o.x = f2bf((v.x - mu) * rstd * gv.x + bv.x);
  o.y = f2bf((v.y - mu) * rstd * gv.y + bv.y);
  o.z = f2bf((v.z - mu) * rstd * gv.z + bv.z);
  o.w = f2bf((v.w - mu) * rstd * gv.w + bv.w);
  ((ushort4*)(out + (size_t)row * 1024))[t] = o;
}

// ---------------- MFMA GEMM: C[M][N] = A[M][K](bf16) * Bt[N][K]^T(bf16) + epilogue ----------------
// EPI 0: QKV mode: cols<2048 -> qk buffer (stride 2048) bf16; cols>=2048 -> vT[b][h][d][n] bf16
// EPI 1: out bf16 = gelu_exact(acc + bias)
// EPI 2: out f32  = resid + (acc + bias) * lsg
template<int EPI>
__global__ __launch_bounds__(256) void k_gemm(
    const unsigned short* __restrict__ A,
    const unsigned short* __restrict__ Bt,
    const float* __restrict__ bias,
    const float* __restrict__ resid,
    const float* __restrict__ lsg,
    void* __restrict__ outp,
    unsigned short* __restrict__ vtp,
    int M, int N, int K)
{
  __shared__ __align__(16) unsigned short Asm[128 * 32];
  __shared__ __align__(16) unsigned short Bsm[128 * 32];
  const int bm = blockIdx.x, bn = blockIdx.y;
  const int t = threadIdx.x, lane = t & 63;
  const int wid = t >> 6, wm = wid >> 1, wn = wid & 1;
  f32x4 acc[4][4] = {};
  const int fr = lane & 15, kc = (lane >> 4) * 8;
  const size_t arow0 = (size_t)bm * 128;
  const size_t brow0 = (size_t)bn * 128;
  const int c0 = t, c1 = 256 + t;
  const int r0c = c0 >> 2, g0c = (c0 & 3) * 8;
  const int r1c = c1 >> 2, g1c = (c1 & 3) * 8;

  for (int kt = 0; kt < K; kt += 32) {
    __syncthreads();
    gload16(A  + (arow0 + r0c) * K + kt + g0c, (char*)Asm + (size_t)c0 * 16);
    gload16(Bt + (brow0 + r0c) * K + kt + g0c, (char*)Bsm + (size_t)c0 * 16);
    gload16(A  + (arow0 + r1c) * K + kt + g1c, (char*)Asm + (size_t)c1 * 16);
    gload16(Bt + (brow0 + r1c) * K + kt + g1c, (char*)Bsm + (size_t)c1 * 16);
    __syncthreads();
    short8 af[4], bfr[4];
    #pragma unroll
    for (int m = 0; m < 4; m++)
      af[m] = *(const short8*)&Asm[(wm*64 + m*16 + fr) * 32 + kc];
    #pragma unroll
    for (int n = 0; n < 4; n++)
      bfr[n] = *(const short8*)&Bsm[(wn*64 + n*16 + fr) * 32 + kc];
    #pragma unroll
    for (int m = 0; m < 4; m++)
      #pragma unroll
      for (int n = 0; n < 4; n++)
        acc[m][n] = MFMA16(af[m], bfr[n], acc[m][n]);
  }

  const int row0 = bm*128 + wm*64 + (lane >> 4) * 4;
  const int col0 = bn*128 + wn*64 + fr;
  #pragma unroll
  for (int n = 0; n < 4; n++) {
    const int col = col0 + n*16;
    const float bcol = bias[col];
    float lscale = 0.f;
    if (EPI == 2) lscale = lsg[col];
    #pragma unroll
    for (int m = 0; m < 4; m++) {
      #pragma unroll
      for (int r = 0; r < 4; r++) {
        const int row = row0 + m*16 + r;
        float v = acc[m][n][r] + bcol;
        if (EPI == 0) {
          if (col < 2048) {
            ((unsigned short*)outp)[(size_t)row * 2048 + col] = f2bf(v);
          } else {
            const int d = col - 2048;
            const int hh = d >> 6, dd = d & 63;
            const int bb = row >> 10, nn = row & 1023;
            vtp[(((size_t)bb * 16 + hh) * 64 + dd) * 1024 + nn] = f2bf(v);
          }
        } else if (EPI == 1) {
          v = 0.5f * v * (1.0f + erff(v * 0.70710678118654752f));
          ((unsigned short*)outp)[(size_t)row * N + col] = f2bf(v);
        } else {
          ((float*)outp)[(size_t)row * N + col] =
              resid[(size_t)row * N + col] + v * lscale;
        }
      }
    }
  }
}

// ---------------- flash attention (no 1/sqrt(d) scale, faithful to ref) ----------------
// qk: [16384][2048] bf16 (row = b*1024+n, col = which*1024 + h*64 + d, which in {Q,K})
// vT: [b][h][64 d][1024 n] bf16
// out: [16384][1024] bf16 (col = h*64 + d)
__global__ __launch_bounds__(512) void k_attn(const unsigned short* __restrict__ qk,
                                              const unsigned short* __restrict__ vT,
                                              unsigned short* __restrict__ out)
{
  const int qt = blockIdx.x;       // 0..3  (q tile of 256 rows)
  const int bh = blockIdx.y;       // 0..255
  const int b = bh >> 4, h = bh & 15;
  const int t = threadIdx.x, lane = t & 63, wid = t >> 6;
  const int fr = lane & 15, fg = lane >> 4;
  const int q0 = qt * 256 + wid * 32;

  __shared__ __align__(16) unsigned short Ksm[64 * 64];     // [kv][d], chunk-swizzled
  __shared__ __align__(16) unsigned short Vsm[64 * 64];     // [d][kv], chunk-swizzled
  __shared__ __align__(16) unsigned short plds[8][32][72];  // per-wave P [q][kv], padded

  const size_t qbase = (size_t)b * 1024 * 2048 + (size_t)h * 64;
  const size_t kbase = qbase + 1024;
  const size_t vbase = (size_t)bh * 64 * 1024;

  // Q fragments: wave owns q rows [q0, q0+32)
  short8 qf[2][2];
  #pragma unroll
  for (int m = 0; m < 2; m++)
    #pragma unroll
    for (int kh = 0; kh < 2; kh++)
      qf[m][kh] = *(const short8*)(qk + qbase + (size_t)(q0 + m*16 + fr) * 2048
                                   + kh*32 + fg*8);

  f32x4 oacc[2][4] = {};
  float mrow[2][4], lrow[2][4];
  #pragma unroll
  for (int m = 0; m < 2; m++)
    #pragma unroll
    for (int r = 0; r < 4; r++) { mrow[m][r] = -1e30f; lrow[m][r] = 0.f; }

  // staging: 512 chunks of 16B per tile; thread t -> (row = t>>3, chunk c = t&7),
  // source chunk pre-swizzled so LDS is linear-dest, swizzled-content (rule #21)
  const int srow = t >> 3, sc = t & 7;
  const int scs = sc ^ (srow & 7);

  for (int kv0 = 0; kv0 < 1024; kv0 += 64) {
    __syncthreads();
    gload16(qk + kbase + (size_t)(kv0 + srow) * 2048 + scs*8, (char*)Ksm + t*16);
    gload16(vT + vbase + (size_t)srow * 1024 + kv0 + scs*8,   (char*)Vsm + t*16);
    __syncthreads();

    // S = Q K^T  (32 x 64 per wave)
    f32x4 sacc[2][4] = {};
    #pragma unroll
    for (int n = 0; n < 4; n++) {
      #pragma unroll
      for (int kh = 0; kh < 2; kh++) {
        const int krow = n*16 + fr;
        short8 kf = *(const short8*)&Ksm[krow*64 + (((kh*4 + fg) ^ (krow & 7)) * 8)];
        sacc[0][n] = MFMA16(qf[0][kh], kf, sacc[0][n]);
        sacc[1][n] = MFMA16(qf[1][kh], kf, sacc[1][n]);
      }
    }

    // online softmax; lane owns rows q = m*16 + fg*4 + r, col = n*16 + fr
    #pragma unroll
    for (int m = 0; m < 2; m++) {
      float pm[4];
      #pragma unroll
      for (int r = 0; r < 4; r++)
        pm[r] = fmaxf(fmaxf(sacc[m][0][r], sacc[m][1][r]),
                      fmaxf(sacc[m][2][r], sacc[m][3][r]));
      #pragma unroll
      for (int msk = 1; msk < 16; msk <<= 1)
        #pragma unroll
        for (int r = 0; r < 4; r++) pm[r] = fmaxf(pm[r], __shfl_xor(pm[r], msk));
      float corr[4];
      #pragma unroll
      for (int r = 0; r < 4; r++) {
        float mn = fmaxf(mrow[m][r], pm[r]);
        corr[r] = __expf(mrow[m][r] - mn);
        mrow[m][r] = mn;
      }
      float psum[4] = {0.f, 0.f, 0.f, 0.f};
      #pragma unroll
      for (int n = 0; n < 4; n++)
        #pragma unroll
        for (int r = 0; r < 4; r++) {
          float p = __expf(sacc[m][n][r] - mrow[m][r]);
          sacc[m][n][r] = p;
          psum[r] += p;
        }
      #pragma unroll
      for (int msk = 1; msk < 16; msk <<= 1)
        #pragma unroll
        for (int r = 0; r < 4; r++) psum[r] += __shfl_xor(psum[r], msk);
      #pragma unroll
      for (int r = 0; r < 4; r++) lrow[m][r] = lrow[m][r] * corr[r] + psum[r];
      #pragma unroll
      for (int d16 = 0; d16 < 4; d16++)
        #pragma unroll
        for (int r = 0; r < 4; r++) oacc[m][d16][r] *= corr[r];
      // P -> per-wave LDS
      #pragma unroll
      for (int n = 0; n < 4; n++)
        #pragma unroll
        for (int r = 0; r < 4; r++)
          plds[wid][m*16 + fg*4 + r][n*16 + fr] = f2bf(sacc[m][n][r]);
    }

    // P fragments
    short8 pf[2][2];
    #pragma unroll
    for (int m = 0; m < 2; m++)
      #pragma unroll
      for (int kh = 0; kh < 2; kh++)
        pf[m][kh] = *(const short8*)&plds[wid][m*16 + fr][kh*32 + fg*8];

    // O += P V
    #pragma unroll
    for (int d16 = 0; d16 < 4; d16++) {
      #pragma unroll
      for (int kh = 0; kh < 2; kh++) {
        const int vrow = d16*16 + fr;
        short8 vf = *(const short8*)&Vsm[vrow*64 + (((kh*4 + fg) ^ (vrow & 7)) * 8)];
        oacc[0][d16] = MFMA16(pf[0][kh], vf, oacc[0][d16]);
        oacc[1][d16] = MFMA16(pf[1][kh], vf, oacc[1][d16]);
      }
    }
  }

  #pragma unroll
  for (int m = 0; m < 2; m++) {
    float inv[4];
    #pragma unroll
    for (int r = 0; r < 4; r++) inv[r] = 1.0f / lrow[m][r];
    #pragma unroll
    for (int d16 = 0; d16 < 4; d16++) {
      #pragma unroll
      for (int r = 0; r < 4; r++) {
        const int qrow = q0 + m*16 + fg*4 + r;
        const int col = h*64 + d16*16 + fr;
        out[(size_t)(b * 1024 + qrow) * 1024 + col] = f2bf(oacc[m][d16][r] * inv[r]);
      }
    }
  }
}

// ---------------- host launch ----------------
extern "C" void kernel_launch(void* const* d_in, const int* in_sizes, int n_in,
                              void* d_out, int out_size, void* d_ws, size_t ws_size,
                              hipStream_t stream) {
  const float* x      = (const float*)d_in[0];
  const float* ln1_g  = (const float*)d_in[1];
  const float* ln1_b  = (const float*)d_in[2];
  const float* qkv_w  = (const float*)d_in[3];
  const float* qkv_b  = (const float*)d_in[4];
  const float* proj_w = (const float*)d_in[5];
  const float* proj_b = (const float*)d_in[6];
  const float* ls1_g  = (const float*)d_in[7];
  const float* ln2_g  = (const float*)d_in[8];
  const float* ln2_b  = (const float*)d_in[9];
  const float* fc1_w  = (const float*)d_in[10];
  const float* fc1_b  = (const float*)d_in[11];
  const float* fc2_w  = (const float*)d_in[12];
  const float* fc2_b  = (const float*)d_in[13];
  const float* ls2_g  = (const float*)d_in[14];

  char* w = (char*)d_ws;
  // workspace layout (bytes)
  unsigned short* wqkvT  = (unsigned short*)(w + 0);                    //  6,291,456
  unsigned short* wprojT = (unsigned short*)(w + 6291456);              //  2,097,152
  unsigned short* wfc1T  = (unsigned short*)(w + 8388608);              //  8,388,608
  unsigned short* wfc2T  = (unsigned short*)(w + 16777216);             //  8,388,608
  float*          x1     = (float*)(w + 25165824);                      // 67,108,864
  unsigned short* h1     = (unsigned short*)(w + 92274688);             // 33,554,432 (reused as h2)
  unsigned short* qkbuf  = (unsigned short*)(w + 125829120);            // 67,108,864 [16384][2048]
  unsigned short* vtbuf  = (unsigned short*)(w + 192937984);            // 33,554,432 [256][64][1024]
  unsigned short* attno  = (unsigned short*)(w + 226492416);            // 33,554,432
  unsigned short* h3     = (unsigned short*)(w + 125829120);            // 134,217,728 (overlays qk+vT+attno? no: qk+vT)

  dim3 tb32(32, 8);
  // weight prep: [K][N] f32 -> [N][K] bf16
  k_transpose_cast<<<dim3(3072/32, 1024/32), tb32, 0, stream>>>(qkv_w,  wqkvT, 1024, 3072);
  k_transpose_cast<<<dim3(1024/32, 1024/32), tb32, 0, stream>>>(proj_w, wprojT, 1024, 1024);
  k_transpose_cast<<<dim3(4096/32, 1024/32), tb32, 0, stream>>>(fc1_w,  wfc1T, 1024, 4096);
  k_transpose_cast<<<dim3(1024/32, 4096/32), tb32, 0, stream>>>(fc2_w,  wfc2T, 4096, 1024);

  // LN1
  k_layernorm<<<16384, 256, 0, stream>>>(x, ln1_g, ln1_b, h1);
  // QKV = h1 @ qkv_w + qkv_b ; Q,K -> qkbuf [16384][2048], V -> vtbuf transposed
  k_gemm<0><<<dim3(128, 24), 256, 0, stream>>>(h1, wqkvT, qkv_b, nullptr, nullptr,
                                               qkbuf, vtbuf, 16384, 3072, 1024);
  // attention
  k_attn<<<dim3(4, 256), 512, 0, stream>>>(qkbuf, vtbuf, attno);
  // x1 = x + (attn @ proj_w + proj_b) * ls1_g
  k_gemm<2><<<dim3(128, 8), 256, 0, stream>>>(attno, wprojT, proj_b, x, ls1_g,
                                              x1, nullptr, 16384, 1024, 1024);
  // LN2
  k_layernorm<<<16384, 256, 0, stream>>>(x1, ln2_g, ln2_b, h1);
  // h3 = gelu(h2 @ fc1_w + fc1_b)  [16384 x 4096]
  k_gemm<1><<<dim3(128, 32), 256, 0, stream>>>(h1, wfc1T, fc1_b, nullptr, nullptr,
                                               h3, nullptr, 16384, 4096, 1024);
  // out = x1 + (h3 @ fc2_w + fc2_b) * ls2_g
  k_gemm<2><<<dim3(128, 8), 256, 0, stream>>>(h3, wfc2T, fc2_b, x1, ls2_g,
                                              (float*)d_out, nullptr, 16384, 1024, 4096);
}